// Round 1
// baseline (757.123 us; speedup 1.0000x reference)
//
#include <hip/hip_runtime.h>

#define NB 8
#define NC 512
#define NPIX 4096
#define LOG2E 1.44269504088896340736f

typedef __attribute__((ext_vector_type(4))) float f32x4;
typedef __attribute__((ext_vector_type(8))) short bf16x8;
typedef __attribute__((ext_vector_type(4))) unsigned short u16x4;

static __device__ __forceinline__ short f2bf(float f){
    union { float f; unsigned u; } v; v.f = f;
    unsigned r = v.u + 0x7fffu + ((v.u >> 16) & 1u);
    return (short)(r >> 16);
}

// ---------------- weight f32 -> bf16 ----------------
__global__ void k_wconv(const float* __restrict__ wq, const float* __restrict__ wk,
                        const float* __restrict__ wv,
                        short* __restrict__ wqb, short* __restrict__ wkb,
                        short* __restrict__ wvb){
    int i = blockIdx.x * 256 + threadIdx.x;
    if (i < 64*NC){ wqb[i] = f2bf(wq[i]); wkb[i] = f2bf(wk[i]); }
    if (i < NC*NC){ wvb[i] = f2bf(wv[i]); }
}

// ---------------- projection ----------------
// out[n][o] bf16 (MODE 0, Q/K, O=64)  or  out[o][n] bf16 (MODE 1, V, O=512)
// X: (C,N) per batch f32 ; W: (O,C) bf16 ; bias: (O,) f32
// D = A*B, A = X^T tile (16n x 32c), B = W^T tile (32c x 16o)
template<int O, int MODE>
__global__ __launch_bounds__(256) void k_proj(const float* __restrict__ X,
                                              const short* __restrict__ W,
                                              const float* __restrict__ bias,
                                              short* __restrict__ out){
    const int b = blockIdx.y;
    const int n0 = blockIdx.x * 16;
    const int wv = threadIdx.x >> 6;
    const int lane = threadIdx.x & 63;
    const int g = lane >> 4, c16 = lane & 15;
    const int NF = O / 64;
    const int o0 = wv * (O/4);

    const float* Xb = X + (size_t)b * NC * NPIX;

    f32x4 acc[NF];
#pragma unroll
    for (int f = 0; f < NF; ++f) acc[f] = (f32x4){0.f,0.f,0.f,0.f};

    for (int c0 = 0; c0 < NC; c0 += 32){
        bf16x8 a;
#pragma unroll
        for (int j = 0; j < 8; ++j)
            a[j] = f2bf(Xb[(size_t)(c0 + 8*g + j) * NPIX + n0 + c16]);
#pragma unroll
        for (int f = 0; f < NF; ++f){
            const short* wp = W + (size_t)(o0 + f*16 + c16) * NC + c0 + 8*g;
            bf16x8 bfr = *(const bf16x8*)wp;
            acc[f] = __builtin_amdgcn_mfma_f32_16x16x32_bf16(a, bfr, acc[f], 0, 0, 0);
        }
    }
    if (MODE == 0){
#pragma unroll
        for (int f = 0; f < NF; ++f){
            int o = o0 + f*16 + c16;
            float bo = bias[o];
#pragma unroll
            for (int i = 0; i < 4; ++i){
                int n = n0 + 4*g + i;
                out[((size_t)b*NPIX + n)*64 + o] = f2bf(acc[f][i] + bo);
            }
        }
    } else {
#pragma unroll
        for (int f = 0; f < NF; ++f){
            int o = o0 + f*16 + c16;
            float bo = bias[o];
            u16x4 pk;
#pragma unroll
            for (int i = 0; i < 4; ++i) pk[i] = (unsigned short)f2bf(acc[f][i] + bo);
            *(u16x4*)(out + ((size_t)b*NC + o)*NPIX + n0 + 4*g) = pk;
        }
    }
}

// ---------------- softmax stats (M, L) ----------------
// Q,K: (B,N,64) bf16. Each wave: 16 query rows, loop all keys in 16-col tiles.
__global__ __launch_bounds__(256) void k_stats(const short* __restrict__ qb,
                                               const short* __restrict__ kb,
                                               float* __restrict__ Mv,
                                               float* __restrict__ Lv){
    const int b = blockIdx.y;
    const int m0 = blockIdx.x * 64;
    const int wv = threadIdx.x >> 6;
    const int lane = threadIdx.x & 63;
    const int g = lane >> 4, c16 = lane & 15;
    const int msub = m0 + wv * 16;

    const short* qrow = qb + ((size_t)b*NPIX + msub + c16) * 64 + 8*g;
    bf16x8 qa0 = *(const bf16x8*)(qrow);
    bf16x8 qa1 = *(const bf16x8*)(qrow + 32);

    float mi[4] = {-1e30f,-1e30f,-1e30f,-1e30f};
    float li[4] = {0.f,0.f,0.f,0.f};

    for (int n0 = 0; n0 < NPIX; n0 += 16){
        const short* kp = kb + ((size_t)b*NPIX + n0 + c16)*64 + 8*g;
        bf16x8 k0 = *(const bf16x8*)kp;
        bf16x8 k1 = *(const bf16x8*)(kp + 32);
        f32x4 s = (f32x4){0.f,0.f,0.f,0.f};
        s = __builtin_amdgcn_mfma_f32_16x16x32_bf16(qa0, k0, s, 0,0,0);
        s = __builtin_amdgcn_mfma_f32_16x16x32_bf16(qa1, k1, s, 0,0,0);
#pragma unroll
        for (int i = 0; i < 4; ++i){
            float sv = s[i];
            float d = sv - mi[i];
            float e = exp2f(-fabsf(d) * LOG2E);   // 1 exp per element, branchless
            bool gt = d > 0.f;
            li[i] = gt ? (li[i]*e + 1.f) : (li[i] + e);
            mi[i] = gt ? sv : mi[i];
        }
    }
#pragma unroll
    for (int off = 1; off < 16; off <<= 1){
#pragma unroll
        for (int i = 0; i < 4; ++i){
            float mo = __shfl_xor(mi[i], off);
            float lo = __shfl_xor(li[i], off);
            float mn = fmaxf(mi[i], mo);
            li[i] = li[i]*exp2f((mi[i]-mn)*LOG2E) + lo*exp2f((mo-mn)*LOG2E);
            mi[i] = mn;
        }
    }
    if (c16 == 0){
#pragma unroll
        for (int i = 0; i < 4; ++i){
            int m = msub + 4*g + i;
            Mv[(size_t)b*NPIX + m] = mi[i];
            Lv[(size_t)b*NPIX + m] = li[i];
        }
    }
}

// ---------------- PV + epilogue ----------------
// block: 512 thr (8 waves), m-tile 64, n-steps of 64.
// Phase A: wave w computes P slice (m-sub (w&3)*16, n-half (w>>2)*32) -> swizzled LDS.
// Phase B: wave w computes out chunk c in [w*64, w*64+64) for all 64 m.
__global__ __launch_bounds__(512, 2) void k_pv(const short* __restrict__ qb,
                                               const short* __restrict__ kb,
                                               const short* __restrict__ vb,
                                               const float* __restrict__ Mv,
                                               const float* __restrict__ Lv,
                                               const float* __restrict__ view1,
                                               const float* __restrict__ gamma,
                                               float* __restrict__ out){
    __shared__ __align__(16) short P[64*64];
    const int b = blockIdx.y;
    const int m0 = blockIdx.x * 64;
    const int wv = threadIdx.x >> 6;
    const int lane = threadIdx.x & 63;
    const int g = lane >> 4, c16 = lane & 15;
    const int msubA = (wv & 3) * 16;
    const int nhalf = wv >> 2;
    const int c0w = wv * 64;

    const short* qrow = qb + ((size_t)b*NPIX + m0 + msubA + c16)*64 + 8*g;
    bf16x8 qa0 = *(const bf16x8*)qrow;
    bf16x8 qa1 = *(const bf16x8*)(qrow + 32);

    float Ma[4], Li[4];
#pragma unroll
    for (int i = 0; i < 4; ++i){
        int m = m0 + msubA + 4*g + i;
        Ma[i] = Mv[(size_t)b*NPIX + m];
        Li[i] = 1.f / Lv[(size_t)b*NPIX + m];
    }

    f32x4 acc[4][4];
#pragma unroll
    for (int f = 0; f < 4; ++f)
#pragma unroll
        for (int cf = 0; cf < 4; ++cf) acc[f][cf] = (f32x4){0.f,0.f,0.f,0.f};

    char* Pb = (char*)P;

    for (int n0 = 0; n0 < NPIX; n0 += 64){
        // ---- Phase A: S -> P (bf16, swizzled LDS) ----
#pragma unroll
        for (int fn = 0; fn < 2; ++fn){
            int nb = n0 + nhalf*32 + fn*16;
            const short* kp = kb + ((size_t)b*NPIX + nb + c16)*64 + 8*g;
            f32x4 s = (f32x4){0.f,0.f,0.f,0.f};
            s = __builtin_amdgcn_mfma_f32_16x16x32_bf16(qa0, *(const bf16x8*)kp, s, 0,0,0);
            s = __builtin_amdgcn_mfma_f32_16x16x32_bf16(qa1, *(const bf16x8*)(kp+32), s, 0,0,0);
            int ncol = nhalf*32 + fn*16 + c16;
#pragma unroll
            for (int i = 0; i < 4; ++i){
                int mrow = msubA + 4*g + i;
                float p = exp2f((s[i]-Ma[i])*LOG2E) * Li[i];
                *(short*)(Pb + mrow*128 + ((ncol*2) ^ ((mrow&7)<<4))) = f2bf(p);
            }
        }
        __syncthreads();
        // ---- Phase B: O += P * V^T ----
#pragma unroll
        for (int h = 0; h < 2; ++h){
            bf16x8 pa[4];
#pragma unroll
            for (int f = 0; f < 4; ++f){
                int row = f*16 + c16;
                pa[f] = *(const bf16x8*)(Pb + row*128 + ((h*64 + g*16) ^ ((row&7)<<4)));
            }
#pragma unroll
            for (int cf = 0; cf < 4; ++cf){
                int c = c0w + cf*16 + c16;
                const short* vp = vb + ((size_t)b*NC + c)*NPIX + n0 + h*32 + 8*g;
                bf16x8 vf = *(const bf16x8*)vp;
#pragma unroll
                for (int f = 0; f < 4; ++f)
                    acc[f][cf] = __builtin_amdgcn_mfma_f32_16x16x32_bf16(pa[f], vf, acc[f][cf], 0,0,0);
            }
        }
        __syncthreads();
    }

    // ---- epilogue: out = gamma*O + view1 (f32) ----
    float gm = gamma[0];
#pragma unroll
    for (int f = 0; f < 4; ++f){
#pragma unroll
        for (int cf = 0; cf < 4; ++cf){
            int c = c0w + cf*16 + c16;
            size_t base = ((size_t)b*NC + c)*NPIX + m0 + f*16 + 4*g;
            f32x4 v1 = *(const f32x4*)(view1 + base);
            f32x4 r;
#pragma unroll
            for (int i = 0; i < 4; ++i) r[i] = gm*acc[f][cf][i] + v1[i];
            *(f32x4*)(out + base) = r;
        }
    }
}

extern "C" void kernel_launch(void* const* d_in, const int* in_sizes, int n_in,
                              void* d_out, int out_size, void* d_ws, size_t ws_size,
                              hipStream_t stream){
    const float* view1 = (const float*)d_in[0];
    const float* view2 = (const float*)d_in[1];
    const float* Wq    = (const float*)d_in[2];
    const float* bq    = (const float*)d_in[3];
    const float* Wk    = (const float*)d_in[4];
    const float* bk    = (const float*)d_in[5];
    const float* Wv    = (const float*)d_in[6];
    const float* bv    = (const float*)d_in[7];
    const float* gamma = (const float*)d_in[8];
    float* out = (float*)d_out;

    char* ws = (char*)d_ws;
    short* qbuf = (short*)(ws);                                  // 4 MB  (B,N,64) bf16
    short* kbuf = (short*)(ws + (size_t)4*1024*1024);            // 4 MB  (B,N,64) bf16
    short* vbuf = (short*)(ws + (size_t)8*1024*1024);            // 32 MB (B,C,N) bf16
    float* Mv   = (float*)(ws + (size_t)40*1024*1024);           // 128 KB
    float* Lv   = (float*)(ws + (size_t)40*1024*1024 + 128*1024);// 128 KB
    short* wqb  = (short*)(ws + (size_t)40*1024*1024 + 256*1024);// 64 KB
    short* wkb  = (short*)(ws + (size_t)40*1024*1024 + 320*1024);// 64 KB
    short* wvb  = (short*)(ws + (size_t)40*1024*1024 + 384*1024);// 512 KB

    hipLaunchKernelGGL(k_wconv, dim3(1024), dim3(256), 0, stream, Wq, Wk, Wv, wqb, wkb, wvb);
    hipLaunchKernelGGL((k_proj<64,0>),  dim3(256, 8), dim3(256), 0, stream, view1, wqb, bq, qbuf);
    hipLaunchKernelGGL((k_proj<64,0>),  dim3(256, 8), dim3(256), 0, stream, view2, wkb, bk, kbuf);
    hipLaunchKernelGGL((k_proj<512,1>), dim3(256, 8), dim3(256), 0, stream, view2, wvb, bv, vbuf);
    hipLaunchKernelGGL(k_stats, dim3(64, 8), dim3(256), 0, stream, qbuf, kbuf, Mv, Lv);
    hipLaunchKernelGGL(k_pv,    dim3(64, 8), dim3(512), 0, stream, qbuf, kbuf, vbuf, Mv, Lv, view1, gamma, out);
}